// Round 3
// baseline (242.264 us; speedup 1.0000x reference)
//
#include <hip/hip_runtime.h>
#include <hip/hip_bf16.h>

#define T_PER_BLK 4
#define XS_ROW 2056          // 2048 uints + 8 pad -> 2-way (free) LDS bank aliasing
#define EPS_F 1e-5f

typedef __bf16 bf16x8 __attribute__((ext_vector_type(8)));
typedef float f32x4 __attribute__((ext_vector_type(4)));

static __device__ __forceinline__ unsigned int pack_bf16x2(float a, float b) {
    union { float f; unsigned int u; } ca, cb;
    ca.f = a; cb.f = b;
    unsigned int ua = (ca.u + 0x7fffu + ((ca.u >> 16) & 1u)) >> 16;
    unsigned int ub = (cb.u + 0x7fffu + ((cb.u >> 16) & 1u)) >> 16;
    return ua | (ub << 16);
}

// ---- setup: wbf[n][k] = bf16(proj_w[n][k] * norm_scale[k]), [48][4096] ----
__global__ void scale_weights(const float* __restrict__ w,
                              const float* __restrict__ ns,
                              unsigned int* __restrict__ wbf)
{
    const int i = (blockIdx.x * 256 + threadIdx.x) * 4;
    const float4 wv = *reinterpret_cast<const float4*>(w + i);
    const float4 nv = *reinterpret_cast<const float4*>(ns + (i & 4095));
    uint2 o;
    o.x = pack_bf16x2(wv.x * nv.x, wv.y * nv.y);
    o.y = pack_bf16x2(wv.z * nv.z, wv.w * nv.w);
    *reinterpret_cast<uint2*>(wbf + (i >> 1)) = o;
}

__global__ __launch_bounds__(256, 4)
void fused_stream_mix(const float* __restrict__ streams,
                      const unsigned short* __restrict__ wbf,   // scaled bf16 weights [48][4096]
                      const float* __restrict__ proj_b,
                      const float* __restrict__ out_scale,
                      float* __restrict__ out)
{
    __shared__ unsigned int xs[T_PER_BLK][XS_ROW];  // 4 tokens x 4096 bf16 packed (~33 KB)
    __shared__ float red[4][3][16][4];              // [kquarter][ntile][col][token] partials
    __shared__ float invr[T_PER_BLK];

    const int tid  = threadIdx.x;
    const int wv   = tid >> 6;        // wave == token owner
    const int lane = tid & 63;
    const size_t tok0 = (size_t)blockIdx.x * T_PER_BLK;

    // ---------- Phase 1: wave wv loads token wv -> LDS bf16, inv RMS ----------
    {
        const float* src = streams + (tok0 + wv) * 4096;
        float ssq = 0.f;
        #pragma unroll
        for (int j = 0; j < 16; ++j) {
            float4 v = *reinterpret_cast<const float4*>(src + j * 256 + lane * 4);
            ssq = fmaf(v.x, v.x, ssq); ssq = fmaf(v.y, v.y, ssq);
            ssq = fmaf(v.z, v.z, ssq); ssq = fmaf(v.w, v.w, ssq);
            const int di = j * 128 + lane * 2;
            xs[wv][di]     = pack_bf16x2(v.x, v.y);
            xs[wv][di + 1] = pack_bf16x2(v.z, v.w);
        }
        #pragma unroll
        for (int m = 32; m >= 1; m >>= 1) ssq += __shfl_xor(ssq, m, 64);
        if (lane == 0) invr[wv] = rsqrtf(ssq * (1.f / 4096.f) + EPS_F);
    }
    __syncthreads();

    // ---------- Phase 2: MFMA projection, split-K across waves ----------
    {
        const int arow = lane & 3;                 // token row (dup'd into rows 4..15)
        const int koff = (lane >> 4) * 8;
        const int bcol = lane & 15;
        const int kbase = wv * 1024;

        const unsigned int* xrow = &xs[arow][0];
        const unsigned short* wp = wbf + (size_t)bcol * 4096 + kbase + koff;

        f32x4 acc0 = {0.f, 0.f, 0.f, 0.f};
        f32x4 acc1 = acc0, acc2 = acc0;

        #pragma unroll 4
        for (int ks = 0; ks < 32; ++ks) {
            const int k = kbase + ks * 32 + koff;
            bf16x8 a  = *reinterpret_cast<const bf16x8*>(&xrow[k >> 1]);
            bf16x8 b0 = *reinterpret_cast<const bf16x8*>(wp + ks * 32);
            bf16x8 b1 = *reinterpret_cast<const bf16x8*>(wp + 16 * 4096 + ks * 32);
            bf16x8 b2 = *reinterpret_cast<const bf16x8*>(wp + 32 * 4096 + ks * 32);
            acc0 = __builtin_amdgcn_mfma_f32_16x16x32_bf16(a, b0, acc0, 0, 0, 0);
            acc1 = __builtin_amdgcn_mfma_f32_16x16x32_bf16(a, b1, acc1, 0, 0, 0);
            acc2 = __builtin_amdgcn_mfma_f32_16x16x32_bf16(a, b2, acc2, 0, 0, 0);
        }
        // D layout: col=lane&15, row=(lane>>4)*4+reg; tokens are rows 0..3 -> lanes 0..15, reg=token
        if (lane < 16) {
            #pragma unroll
            for (int r = 0; r < 4; ++r) {
                red[wv][0][lane][r] = acc0[r];
                red[wv][1][lane][r] = acc1[r];
                red[wv][2][lane][r] = acc2[r];
            }
        }
    }
    __syncthreads();

    // ---------- Phase 3: each wave redundantly builds M for its own token (reg-only) ----------
    float Mr[16];
    {
        float raw[48];
        const float ir = invr[wv];
        #pragma unroll
        for (int tile = 0; tile < 3; ++tile)
            #pragma unroll
            for (int col = 0; col < 16; ++col) {
                const float s = red[0][tile][col][wv] + red[1][tile][col][wv]
                              + red[2][tile][col][wv] + red[3][tile][col][wv];
                raw[tile * 16 + col] = s * ir + proj_b[tile * 16 + col];
            }

        // H_pre row-softmax -> c[j] = 0.25 * column sums
        float c[4] = {0.f, 0.f, 0.f, 0.f};
        #pragma unroll
        for (int i = 0; i < 4; ++i) {
            const float a0 = raw[i*4+0], a1 = raw[i*4+1], a2 = raw[i*4+2], a3 = raw[i*4+3];
            const float m = fmaxf(fmaxf(a0, a1), fmaxf(a2, a3));
            const float e0 = expf(a0 - m), e1 = expf(a1 - m);
            const float e2 = expf(a2 - m), e3 = expf(a3 - m);
            const float inv = 1.f / (e0 + e1 + e2 + e3);
            c[0] = fmaf(e0, inv, c[0]); c[1] = fmaf(e1, inv, c[1]);
            c[2] = fmaf(e2, inv, c[2]); c[3] = fmaf(e3, inv, c[3]);
        }
        c[0] *= 0.25f; c[1] *= 0.25f; c[2] *= 0.25f; c[3] *= 0.25f;

        // H_post column-softmax -> rs[i] = row sums
        float rs[4] = {0.f, 0.f, 0.f, 0.f};
        #pragma unroll
        for (int j = 0; j < 4; ++j) {
            const float b0 = raw[16+j], b1 = raw[16+4+j], b2 = raw[16+8+j], b3 = raw[16+12+j];
            const float m = fmaxf(fmaxf(b0, b1), fmaxf(b2, b3));
            const float e0 = expf(b0 - m), e1 = expf(b1 - m);
            const float e2 = expf(b2 - m), e3 = expf(b3 - m);
            const float inv = 1.f / (e0 + e1 + e2 + e3);
            rs[0] = fmaf(e0, inv, rs[0]); rs[1] = fmaf(e1, inv, rs[1]);
            rs[2] = fmaf(e2, inv, rs[2]); rs[3] = fmaf(e3, inv, rs[3]);
        }

        // Cayley iterative on raw[32..47]
        float W[16], Y[16];
        #pragma unroll
        for (int i = 0; i < 4; ++i)
            #pragma unroll
            for (int j = 0; j < 4; ++j)
                W[i*4+j] = raw[32 + i*4+j] - raw[32 + j*4+i];
        #pragma unroll
        for (int i = 0; i < 16; ++i) Y[i] = 0.1f * W[i];
        Y[0] += 1.f; Y[5] += 1.f; Y[10] += 1.f; Y[15] += 1.f;
        #pragma unroll
        for (int it = 0; it < 2; ++it) {
            float T1[16];
            #pragma unroll
            for (int i = 0; i < 16; ++i) T1[i] = Y[i];
            T1[0] += 1.f; T1[5] += 1.f; T1[10] += 1.f; T1[15] += 1.f;
            float Yn[16];
            #pragma unroll
            for (int i = 0; i < 4; ++i)
                #pragma unroll
                for (int j = 0; j < 4; ++j) {
                    float s = W[i*4+0] * T1[0*4+j];
                    s = fmaf(W[i*4+1], T1[1*4+j], s);
                    s = fmaf(W[i*4+2], T1[2*4+j], s);
                    s = fmaf(W[i*4+3], T1[3*4+j], s);
                    Yn[i*4+j] = ((i == j) ? 1.f : 0.f) + 0.05f * s;
                }
            #pragma unroll
            for (int i = 0; i < 16; ++i) Y[i] = Yn[i];
        }

        const float os = out_scale[0];
        #pragma unroll
        for (int i = 0; i < 4; ++i)
            #pragma unroll
            for (int j = 0; j < 4; ++j)
                Mr[i*4+j] = Y[i*4+j] + os * rs[i] * c[j];
    }
    // no barrier needed: phase 4 reads only xs[wv] (written by this wave in phase 1)

    // ---------- Phase 4: out[token wv] = M @ streams, float4 stores ----------
    {
        float* dst = out + (tok0 + wv) * 4096;
        #pragma unroll
        for (int it = 0; it < 4; ++it) {
            const int cq = it * 64 + lane;     // column-quad 0..255
            float x[4][4];
            #pragma unroll
            for (int j = 0; j < 4; ++j) {
                const uint2 u = *reinterpret_cast<const uint2*>(&xs[wv][j * 512 + cq * 2]);
                x[j][0] = __uint_as_float(u.x << 16);
                x[j][1] = __uint_as_float(u.x & 0xffff0000u);
                x[j][2] = __uint_as_float(u.y << 16);
                x[j][3] = __uint_as_float(u.y & 0xffff0000u);
            }
            #pragma unroll
            for (int i = 0; i < 4; ++i) {
                float4 o;
                o.x = Mr[i*4+0]*x[0][0]; o.y = Mr[i*4+0]*x[0][1];
                o.z = Mr[i*4+0]*x[0][2]; o.w = Mr[i*4+0]*x[0][3];
                #pragma unroll
                for (int j = 1; j < 4; ++j) {
                    o.x = fmaf(Mr[i*4+j], x[j][0], o.x);
                    o.y = fmaf(Mr[i*4+j], x[j][1], o.y);
                    o.z = fmaf(Mr[i*4+j], x[j][2], o.z);
                    o.w = fmaf(Mr[i*4+j], x[j][3], o.w);
                }
                *reinterpret_cast<float4*>(dst + i * 1024 + cq * 4) = o;
            }
        }
    }
}

extern "C" void kernel_launch(void* const* d_in, const int* in_sizes, int n_in,
                              void* d_out, int out_size, void* d_ws, size_t ws_size,
                              hipStream_t stream) {
    const float* streams    = (const float*)d_in[0];
    const float* norm_scale = (const float*)d_in[1];
    const float* proj_w     = (const float*)d_in[2];
    const float* proj_b     = (const float*)d_in[3];
    const float* out_scale  = (const float*)d_in[4];
    float* outp = (float*)d_out;

    unsigned int* wbf = (unsigned int*)d_ws;       // 48*4096 bf16 = 393216 B

    scale_weights<<<dim3(192), 256, 0, stream>>>(proj_w, norm_scale, wbf);

    const int n_tok = in_sizes[0] / 4096;          // B*S = 16384
    dim3 grid(n_tok / T_PER_BLK);                  // 4096 blocks
    fused_stream_mix<<<grid, 256, 0, stream>>>(streams,
                                               (const unsigned short*)wbf,
                                               proj_b, out_scale, outp);
}

// Round 4
// 168.928 us; speedup vs baseline: 1.4341x; 1.4341x over previous
//
#include <hip/hip_runtime.h>
#include <hip/hip_bf16.h>

#define T_PER_BLK 8
#define XS_ROW 2060          // 2048 uints + 12 pad: rows 0..7 land on 8 distinct banks
#define EPS_F 1e-5f

typedef __bf16 bf16x8 __attribute__((ext_vector_type(8)));
typedef float f32x4 __attribute__((ext_vector_type(4)));

static __device__ __forceinline__ unsigned int pack_bf16x2(float a, float b) {
    union { float f; unsigned int u; } ca, cb;
    ca.f = a; cb.f = b;
    unsigned int ua = (ca.u + 0x7fffu + ((ca.u >> 16) & 1u)) >> 16;
    unsigned int ub = (cb.u + 0x7fffu + ((cb.u >> 16) & 1u)) >> 16;
    return ua | (ub << 16);
}

// ---- setup: wbf[n][k] = bf16(proj_w[n][k] * norm_scale[k]), [48][4096] ----
__global__ void scale_weights(const float* __restrict__ w,
                              const float* __restrict__ ns,
                              unsigned int* __restrict__ wbf)
{
    const int i = (blockIdx.x * 256 + threadIdx.x) * 4;
    const float4 wv = *reinterpret_cast<const float4*>(w + i);
    const float4 nv = *reinterpret_cast<const float4*>(ns + (i & 4095));
    uint2 o;
    o.x = pack_bf16x2(wv.x * nv.x, wv.y * nv.y);
    o.y = pack_bf16x2(wv.z * nv.z, wv.w * nv.w);
    *reinterpret_cast<uint2*>(wbf + (i >> 1)) = o;
}

__global__ __launch_bounds__(512, 4)
void fused_stream_mix(const float* __restrict__ streams,
                      const unsigned short* __restrict__ wbf,   // scaled bf16 weights [48][4096]
                      const float* __restrict__ proj_b,
                      const float* __restrict__ out_scale,
                      float* __restrict__ out)
{
    __shared__ unsigned int xs[T_PER_BLK][XS_ROW];  // 8 tokens x 4096 bf16 packed (~66 KB)
    __shared__ float red[8][3][8][16];              // [kpart][ntile][tokenrow][col] = 12 KB

    const int tid  = threadIdx.x;
    const int wv   = tid >> 6;        // wave == token owner == K-part
    const int lane = tid & 63;
    const size_t tok0 = (size_t)blockIdx.x * T_PER_BLK;

    // ---------- Phase 1: wave wv loads token wv -> LDS bf16, inv RMS (kept in regs) ----------
    float invr;
    {
        const float* src = streams + (tok0 + wv) * 4096;
        float ssq = 0.f;
        #pragma unroll
        for (int j = 0; j < 16; ++j) {
            float4 v = *reinterpret_cast<const float4*>(src + j * 256 + lane * 4);
            ssq = fmaf(v.x, v.x, ssq); ssq = fmaf(v.y, v.y, ssq);
            ssq = fmaf(v.z, v.z, ssq); ssq = fmaf(v.w, v.w, ssq);
            const int di = j * 128 + lane * 2;
            xs[wv][di]     = pack_bf16x2(v.x, v.y);
            xs[wv][di + 1] = pack_bf16x2(v.z, v.w);
        }
        #pragma unroll
        for (int m = 32; m >= 1; m >>= 1) ssq += __shfl_xor(ssq, m, 64);
        invr = rsqrtf(ssq * (1.f / 4096.f) + EPS_F);
    }
    __syncthreads();

    // ---------- Phase 2: MFMA projection, 8-way split-K across waves ----------
    {
        const int arow = lane & 7;                 // token row (dup'd into rows 8..15)
        const int koff = (lane >> 4) * 8;
        const int bcol = lane & 15;
        const int kbase = wv * 512;                // this wave's K eighth

        const unsigned int* xrow = &xs[arow][0];
        const unsigned short* wp = wbf + (size_t)bcol * 4096 + kbase + koff;

        f32x4 acc0 = {0.f, 0.f, 0.f, 0.f};
        f32x4 acc1 = acc0, acc2 = acc0;

        #pragma unroll 4
        for (int ks = 0; ks < 16; ++ks) {
            const int k = kbase + ks * 32 + koff;
            bf16x8 a  = *reinterpret_cast<const bf16x8*>(&xrow[k >> 1]);
            bf16x8 b0 = *reinterpret_cast<const bf16x8*>(wp + ks * 32);
            bf16x8 b1 = *reinterpret_cast<const bf16x8*>(wp + 16 * 4096 + ks * 32);
            bf16x8 b2 = *reinterpret_cast<const bf16x8*>(wp + 32 * 4096 + ks * 32);
            acc0 = __builtin_amdgcn_mfma_f32_16x16x32_bf16(a, b0, acc0, 0, 0, 0);
            acc1 = __builtin_amdgcn_mfma_f32_16x16x32_bf16(a, b1, acc1, 0, 0, 0);
            acc2 = __builtin_amdgcn_mfma_f32_16x16x32_bf16(a, b2, acc2, 0, 0, 0);
        }
        // D layout: col=lane&15, row=(lane>>4)*4+reg; tokens 0..7 live in lanes 0..31
        if (lane < 32) {
            const int col = lane & 15, rg = (lane >> 4) * 4;
            #pragma unroll
            for (int r = 0; r < 4; ++r) {
                red[wv][0][rg + r][col] = acc0[r];
                red[wv][1][rg + r][col] = acc1[r];
                red[wv][2][rg + r][col] = acc2[r];
            }
        }
    }
    __syncthreads();

    // ---------- Phase 3: wave wv builds M for its token (reg-only, redundant per lane) ----------
    float Mr[16];
    {
        float raw[48];
        #pragma unroll
        for (int tile = 0; tile < 3; ++tile) {
            #pragma unroll
            for (int c4 = 0; c4 < 4; ++c4) {
                f32x4 s = {0.f, 0.f, 0.f, 0.f};
                #pragma unroll
                for (int kp = 0; kp < 8; ++kp) {
                    const f32x4 v = *reinterpret_cast<const f32x4*>(&red[kp][tile][wv][c4 * 4]);
                    s += v;
                }
                const float4 pb = *reinterpret_cast<const float4*>(&proj_b[tile * 16 + c4 * 4]);
                raw[tile*16 + c4*4 + 0] = s[0] * invr + pb.x;
                raw[tile*16 + c4*4 + 1] = s[1] * invr + pb.y;
                raw[tile*16 + c4*4 + 2] = s[2] * invr + pb.z;
                raw[tile*16 + c4*4 + 3] = s[3] * invr + pb.w;
            }
        }

        // H_pre row-softmax -> c[j] = 0.25 * column sums
        float c[4] = {0.f, 0.f, 0.f, 0.f};
        #pragma unroll
        for (int i = 0; i < 4; ++i) {
            const float a0 = raw[i*4+0], a1 = raw[i*4+1], a2 = raw[i*4+2], a3 = raw[i*4+3];
            const float m = fmaxf(fmaxf(a0, a1), fmaxf(a2, a3));
            const float e0 = expf(a0 - m), e1 = expf(a1 - m);
            const float e2 = expf(a2 - m), e3 = expf(a3 - m);
            const float inv = 1.f / (e0 + e1 + e2 + e3);
            c[0] = fmaf(e0, inv, c[0]); c[1] = fmaf(e1, inv, c[1]);
            c[2] = fmaf(e2, inv, c[2]); c[3] = fmaf(e3, inv, c[3]);
        }
        c[0] *= 0.25f; c[1] *= 0.25f; c[2] *= 0.25f; c[3] *= 0.25f;

        // H_post column-softmax -> rs[i] = row sums
        float rs[4] = {0.f, 0.f, 0.f, 0.f};
        #pragma unroll
        for (int j = 0; j < 4; ++j) {
            const float b0 = raw[16+j], b1 = raw[16+4+j], b2 = raw[16+8+j], b3 = raw[16+12+j];
            const float m = fmaxf(fmaxf(b0, b1), fmaxf(b2, b3));
            const float e0 = expf(b0 - m), e1 = expf(b1 - m);
            const float e2 = expf(b2 - m), e3 = expf(b3 - m);
            const float inv = 1.f / (e0 + e1 + e2 + e3);
            rs[0] = fmaf(e0, inv, rs[0]); rs[1] = fmaf(e1, inv, rs[1]);
            rs[2] = fmaf(e2, inv, rs[2]); rs[3] = fmaf(e3, inv, rs[3]);
        }

        // Cayley iterative on raw[32..47]
        float W[16], Y[16];
        #pragma unroll
        for (int i = 0; i < 4; ++i)
            #pragma unroll
            for (int j = 0; j < 4; ++j)
                W[i*4+j] = raw[32 + i*4+j] - raw[32 + j*4+i];
        #pragma unroll
        for (int i = 0; i < 16; ++i) Y[i] = 0.1f * W[i];
        Y[0] += 1.f; Y[5] += 1.f; Y[10] += 1.f; Y[15] += 1.f;
        #pragma unroll
        for (int it = 0; it < 2; ++it) {
            float T1[16];
            #pragma unroll
            for (int i = 0; i < 16; ++i) T1[i] = Y[i];
            T1[0] += 1.f; T1[5] += 1.f; T1[10] += 1.f; T1[15] += 1.f;
            float Yn[16];
            #pragma unroll
            for (int i = 0; i < 4; ++i)
                #pragma unroll
                for (int j = 0; j < 4; ++j) {
                    float s = W[i*4+0] * T1[0*4+j];
                    s = fmaf(W[i*4+1], T1[1*4+j], s);
                    s = fmaf(W[i*4+2], T1[2*4+j], s);
                    s = fmaf(W[i*4+3], T1[3*4+j], s);
                    Yn[i*4+j] = ((i == j) ? 1.f : 0.f) + 0.05f * s;
                }
            #pragma unroll
            for (int i = 0; i < 16; ++i) Y[i] = Yn[i];
        }

        const float os = out_scale[0];
        #pragma unroll
        for (int i = 0; i < 4; ++i)
            #pragma unroll
            for (int j = 0; j < 4; ++j)
                Mr[i*4+j] = Y[i*4+j] + os * rs[i] * c[j];
    }
    // no barrier: phase 4 reads xs[wv], written by this wave in phase 1; nothing overwrites xs

    // ---------- Phase 4: out[token wv] = M @ streams, float4 stores ----------
    {
        float* dst = out + (tok0 + wv) * 4096;
        #pragma unroll
        for (int it = 0; it < 4; ++it) {
            const int cq = it * 64 + lane;     // column-quad 0..255
            float x[4][4];
            #pragma unroll
            for (int j = 0; j < 4; ++j) {
                const uint2 u = *reinterpret_cast<const uint2*>(&xs[wv][j * 512 + cq * 2]);
                x[j][0] = __uint_as_float(u.x << 16);
                x[j][1] = __uint_as_float(u.x & 0xffff0000u);
                x[j][2] = __uint_as_float(u.y << 16);
                x[j][3] = __uint_as_float(u.y & 0xffff0000u);
            }
            #pragma unroll
            for (int i = 0; i < 4; ++i) {
                float4 o;
                o.x = Mr[i*4+0]*x[0][0]; o.y = Mr[i*4+0]*x[0][1];
                o.z = Mr[i*4+0]*x[0][2]; o.w = Mr[i*4+0]*x[0][3];
                #pragma unroll
                for (int j = 1; j < 4; ++j) {
                    o.x = fmaf(Mr[i*4+j], x[j][0], o.x);
                    o.y = fmaf(Mr[i*4+j], x[j][1], o.y);
                    o.z = fmaf(Mr[i*4+j], x[j][2], o.z);
                    o.w = fmaf(Mr[i*4+j], x[j][3], o.w);
                }
                *reinterpret_cast<float4*>(dst + i * 1024 + cq * 4) = o;
            }
        }
    }
}

extern "C" void kernel_launch(void* const* d_in, const int* in_sizes, int n_in,
                              void* d_out, int out_size, void* d_ws, size_t ws_size,
                              hipStream_t stream) {
    const float* streams    = (const float*)d_in[0];
    const float* norm_scale = (const float*)d_in[1];
    const float* proj_w     = (const float*)d_in[2];
    const float* proj_b     = (const float*)d_in[3];
    const float* out_scale  = (const float*)d_in[4];
    float* outp = (float*)d_out;

    unsigned int* wbf = (unsigned int*)d_ws;       // 48*4096 bf16 = 393216 B

    scale_weights<<<dim3(192), 256, 0, stream>>>(proj_w, norm_scale, wbf);

    const int n_tok = in_sizes[0] / 4096;          // B*S = 16384
    dim3 grid(n_tok / T_PER_BLK);                  // 2048 blocks
    fused_stream_mix<<<grid, 512, 0, stream>>>(streams,
                                               (const unsigned short*)wbf,
                                               proj_b, out_scale, outp);
}